// Round 4
// baseline (46.709 us; speedup 1.0000x reference)
//
#include <hip/hip_runtime.h>

// Problem constants: B=256, P=64, D=1024, MARGIN=0.1
constexpr int NB = 256;
constexpr int NP = 64;
constexpr int ND = 1024;
constexpr float MARGIN = 0.1f;

typedef __attribute__((ext_vector_type(8))) short bf16x8;  // 8 bf16 (4 VGPRs)
typedef __attribute__((ext_vector_type(4))) short bf16x4;  // 4 bf16 (2 VGPRs)
typedef __attribute__((ext_vector_type(4))) float f32x4;   // MFMA accumulator

// fp32 -> bf16 round-to-nearest-even (inputs are finite gaussians; no NaN path)
static __device__ inline unsigned short f2bf(float f) {
  unsigned u = __builtin_bit_cast(unsigned, f);
  u += 0x7fffu + ((u >> 16) & 1u);
  return (unsigned short)(u >> 16);
}

static __device__ inline bf16x8 cvt8(float4 a, float4 b) {
  bf16x8 r;
  r[0] = (short)f2bf(a.x); r[1] = (short)f2bf(a.y);
  r[2] = (short)f2bf(a.z); r[3] = (short)f2bf(a.w);
  r[4] = (short)f2bf(b.x); r[5] = (short)f2bf(b.y);
  r[6] = (short)f2bf(b.z); r[7] = (short)f2bf(b.w);
  return r;
}

// ---------------------------------------------------------------------------
// Kernel 0: disFtr fp32 -> bf16, once. 256x1024 elems, 4/thread.
// ---------------------------------------------------------------------------
__global__ __launch_bounds__(256) void cvtB_kernel(
    const float* __restrict__ src, short* __restrict__ dst) {
  const int idx = (blockIdx.x * 256 + threadIdx.x) * 4;
  float4 v = *reinterpret_cast<const float4*>(src + idx);
  bf16x4 r;
  r[0] = (short)f2bf(v.x); r[1] = (short)f2bf(v.y);
  r[2] = (short)f2bf(v.z); r[3] = (short)f2bf(v.w);
  *reinterpret_cast<bf16x4*>(dst + idx) = r;
}

// ---------------------------------------------------------------------------
// Kernel 1: simHalf[ph][i][c] = max_{p in half ph} sum_d imFtr[i][p][d]*disB[c][d]
// grid=(256,2), 512 threads = 8 waves. Wave w owns c in [w*32, w*32+32).
// K-chunk 128, double-buffered LDS A (one barrier per chunk), chunk n+1's
// A (global fp32->cvt) and B (global bf16) loads issued before chunk n's MFMAs.
// LDS swizzle: A[row][k] at [row][ ((k/8) ^ (row&7))*8 + k%8 ] -> conflict-free
// b128 reads/writes (8 consecutive lanes span 8 distinct 16B slots = 32 banks).
// MFMA D layout: row(p-part)=(l>>4)*4+reg, col(c-part)=l&15.
// ---------------------------------------------------------------------------
__global__ __launch_bounds__(512) void simmax_half_kernel(
    const float* __restrict__ imFtr, const short* __restrict__ disB,
    float* __restrict__ simHalf) {
  const int i  = blockIdx.x;
  const int ph = blockIdx.y;
  const int t  = threadIdx.x;
  const int w  = t >> 6;   // wave 0..7
  const int l  = t & 63;
  const int lr = l & 15;   // tile row (A) / tile col (B,D)
  const int lk = l >> 4;   // k-group 0..3

  __shared__ short Asl[2][32][128];  // 16 KB, double-buffered A chunk (bf16)

  f32x4 acc[2][2];  // [pt][ct]
#pragma unroll
  for (int pt = 0; pt < 2; ++pt)
#pragma unroll
    for (int ct = 0; ct < 2; ++ct)
#pragma unroll
      for (int r = 0; r < 4; ++r) acc[pt][ct][r] = 0.0f;

  // A staging: thread -> row ar (0..31), k-slot aks (0..15, 8 fp32 each)
  const int ar  = t >> 4;
  const int aks = t & 15;
  const float* ap = imFtr + ((size_t)i * NP + ph * 32 + ar) * ND + aks * 8;
  short* awp0 = &Asl[0][ar][(aks ^ (ar & 7)) * 8];
  short* awp1 = &Asl[1][ar][(aks ^ (ar & 7)) * 8];

  // B pointers: wave-local c rows, lane-local k offset handled per load
  const short* bp0 = disB + (size_t)(w * 32 + lr) * ND + lk * 8;
  const short* bp1 = disB + (size_t)(w * 32 + 16 + lr) * ND + lk * 8;

  // --- prologue: chunk 0 ---
  float4 a0 = *reinterpret_cast<const float4*>(ap);
  float4 a1 = *reinterpret_cast<const float4*>(ap + 4);
  bf16x8 breg[4][2];
#pragma unroll
  for (int ks = 0; ks < 4; ++ks) {
    breg[ks][0] = *reinterpret_cast<const bf16x8*>(bp0 + ks * 32);
    breg[ks][1] = *reinterpret_cast<const bf16x8*>(bp1 + ks * 32);
  }
  *reinterpret_cast<bf16x8*>(awp0) = cvt8(a0, a1);
  __syncthreads();

#pragma unroll
  for (int kc = 0; kc < 8; ++kc) {
    // issue next chunk's loads first (hide latency under this chunk's MFMAs)
    float4 an0, an1;
    bf16x8 bnext[4][2];
    if (kc < 7) {
      const float* apn = ap + (kc + 1) * 128;
      an0 = *reinterpret_cast<const float4*>(apn);
      an1 = *reinterpret_cast<const float4*>(apn + 4);
      const int kb = (kc + 1) * 128;
#pragma unroll
      for (int ks = 0; ks < 4; ++ks) {
        bnext[ks][0] = *reinterpret_cast<const bf16x8*>(bp0 + kb + ks * 32);
        bnext[ks][1] = *reinterpret_cast<const bf16x8*>(bp1 + kb + ks * 32);
      }
    }
    // compute chunk kc from buf[kc&1]
    const int cb = kc & 1;
#pragma unroll
    for (int ks = 0; ks < 4; ++ks) {
#pragma unroll
      for (int pt = 0; pt < 2; ++pt) {
        const int row  = pt * 16 + lr;
        const int slot = ((ks * 4 + lk) ^ (row & 7)) * 8;
        bf16x8 afr = *reinterpret_cast<const bf16x8*>(&Asl[cb][row][slot]);
        acc[pt][0] = __builtin_amdgcn_mfma_f32_16x16x32_bf16(afr, breg[ks][0], acc[pt][0], 0, 0, 0);
        acc[pt][1] = __builtin_amdgcn_mfma_f32_16x16x32_bf16(afr, breg[ks][1], acc[pt][1], 0, 0, 0);
      }
    }
    if (kc < 7) {
      bf16x8 aw = cvt8(an0, an1);
      if ((kc & 1) == 0) *reinterpret_cast<bf16x8*>(awp1) = aw;
      else               *reinterpret_cast<bf16x8*>(awp0) = aw;
      __syncthreads();  // single barrier per chunk (dbuf makes it sufficient)
#pragma unroll
      for (int ks = 0; ks < 4; ++ks) {
        breg[ks][0] = bnext[ks][0];
        breg[ks][1] = bnext[ks][1];
      }
    }
  }

  // max over p-half: 8 per-lane values (2 pt x 4 r), then across k-groups
#pragma unroll
  for (int ct = 0; ct < 2; ++ct) {
    float m = acc[0][ct][0];
#pragma unroll
    for (int pt = 0; pt < 2; ++pt)
#pragma unroll
      for (int r = 0; r < 4; ++r) m = fmaxf(m, acc[pt][ct][r]);
    m = fmaxf(m, __shfl_xor(m, 16));
    m = fmaxf(m, __shfl_xor(m, 32));
    if (l < 16)
      simHalf[((size_t)ph * NB + i) * NB + w * 32 + ct * 16 + l] = m;
  }
}

// ---------------------------------------------------------------------------
// Fallback simmax (R2 path, fused cvt, needs only 259 KB ws). grid=256, 512 thr.
// ---------------------------------------------------------------------------
__global__ __launch_bounds__(512) void simmax_fallback_kernel(
    const float* __restrict__ imFtr, const float* __restrict__ disFtr,
    float* __restrict__ simMax) {
  const int i  = blockIdx.x;
  const int t  = threadIdx.x;
  const int w  = t >> 6;
  const int l  = t & 63;
  const int lr = l & 15;
  const int lk = l >> 4;

  __shared__ short Asl[NP][64];

  f32x4 acc[4][2];
#pragma unroll
  for (int pt = 0; pt < 4; ++pt)
#pragma unroll
    for (int ct = 0; ct < 2; ++ct)
#pragma unroll
      for (int r = 0; r < 4; ++r) acc[pt][ct][r] = 0.0f;

  const int ar  = t >> 3;
  const int aks = t & 7;
  const float* ap = imFtr + (size_t)i * NP * ND + (size_t)ar * ND + aks * 8;
  const int wslot = ((aks ^ (ar & 7)) * 8);
  float4 av0 = *reinterpret_cast<const float4*>(ap);
  float4 av1 = *reinterpret_cast<const float4*>(ap + 4);

  const float* bp0 = disFtr + (size_t)(w * 32 + lr) * ND + lk * 8;
  const float* bp1 = disFtr + (size_t)(w * 32 + 16 + lr) * ND + lk * 8;

  for (int kc = 0; kc < 16; ++kc) {
    const int kbase = kc * 64;
    float4 bld[2][2][2];
#pragma unroll
    for (int ks = 0; ks < 2; ++ks) {
      const int ko = kbase + ks * 32;
      bld[ks][0][0] = *reinterpret_cast<const float4*>(bp0 + ko);
      bld[ks][0][1] = *reinterpret_cast<const float4*>(bp0 + ko + 4);
      bld[ks][1][0] = *reinterpret_cast<const float4*>(bp1 + ko);
      bld[ks][1][1] = *reinterpret_cast<const float4*>(bp1 + ko + 4);
    }
    __syncthreads();
    *reinterpret_cast<bf16x8*>(&Asl[ar][wslot]) = cvt8(av0, av1);
    if (kc < 15) {
      const float* apn = ap + (kc + 1) * 64;
      av0 = *reinterpret_cast<const float4*>(apn);
      av1 = *reinterpret_cast<const float4*>(apn + 4);
    }
    __syncthreads();

#pragma unroll
    for (int ks = 0; ks < 2; ++ks) {
      bf16x8 bfr0 = cvt8(bld[ks][0][0], bld[ks][0][1]);
      bf16x8 bfr1 = cvt8(bld[ks][1][0], bld[ks][1][1]);
#pragma unroll
      for (int pt = 0; pt < 4; ++pt) {
        const int row  = pt * 16 + lr;
        const int slot = (((ks * 4 + lk) ^ (row & 7)) * 8);
        bf16x8 afr = *reinterpret_cast<const bf16x8*>(&Asl[row][slot]);
        acc[pt][0] = __builtin_amdgcn_mfma_f32_16x16x32_bf16(afr, bfr0, acc[pt][0], 0, 0, 0);
        acc[pt][1] = __builtin_amdgcn_mfma_f32_16x16x32_bf16(afr, bfr1, acc[pt][1], 0, 0, 0);
      }
    }
  }

#pragma unroll
  for (int ct = 0; ct < 2; ++ct) {
    float m = acc[0][ct][0];
#pragma unroll
    for (int pt = 0; pt < 4; ++pt)
#pragma unroll
      for (int r = 0; r < 4; ++r) m = fmaxf(m, acc[pt][ct][r]);
    m = fmaxf(m, __shfl_xor(m, 16));
    m = fmaxf(m, __shfl_xor(m, 32));
    if (l < 16) simMax[(size_t)i * NB + w * 32 + ct * 16 + l] = m;
  }
}

// ---------------------------------------------------------------------------
// Kernel 2: per-row partial sums {mask count, loss_it, loss_ti}.
// Takes two simMax buffers and maxes them (pass the same pointer twice for
// the non-split path).
// ---------------------------------------------------------------------------
__global__ __launch_bounds__(256) void loss_kernel(
    const float* __restrict__ sh0, const float* __restrict__ sh1,
    const int* __restrict__ lbl, float* __restrict__ partial) {
  const int i = blockIdx.x;
  const int j = threadIdx.x;
  __shared__ float posi_sh;
  __shared__ float red[3][4];

  float s = fmaxf(sh0[(size_t)i * NB + j], sh1[(size_t)i * NB + j]);
  if (j == i) posi_sh = s;
  __syncthreads();
  const float posi = posi_sh;
  const float posj = fmaxf(sh0[(size_t)j * NB + j], sh1[(size_t)j * NB + j]);

  const float msk = (lbl[i] != lbl[j]) ? 1.0f : 0.0f;
  float c  = msk;
  float l1 = msk * fmaxf(s - posi + MARGIN, 0.0f);
  float l2 = msk * fmaxf(s - posj + MARGIN, 0.0f);
#pragma unroll
  for (int o = 32; o > 0; o >>= 1) {
    c  += __shfl_down(c, o);
    l1 += __shfl_down(l1, o);
    l2 += __shfl_down(l2, o);
  }
  const int w = j >> 6;
  if ((j & 63) == 0) { red[0][w] = c; red[1][w] = l1; red[2][w] = l2; }
  __syncthreads();
  if (j == 0) {
    partial[i * 3 + 0] = red[0][0] + red[0][1] + red[0][2] + red[0][3];
    partial[i * 3 + 1] = red[1][0] + red[1][1] + red[1][2] + red[1][3];
    partial[i * 3 + 2] = red[2][0] + red[2][1] + red[2][2] + red[2][3];
  }
}

// ---------------------------------------------------------------------------
// Kernel 3: final reduction over 256 row-partials -> loss scalar.
// ---------------------------------------------------------------------------
__global__ __launch_bounds__(256) void finalize_kernel(
    const float* __restrict__ partial, float* __restrict__ out) {
  const int t = threadIdx.x;
  __shared__ float red[3][4];
  float c  = partial[t * 3 + 0];
  float l1 = partial[t * 3 + 1];
  float l2 = partial[t * 3 + 2];
#pragma unroll
  for (int o = 32; o > 0; o >>= 1) {
    c  += __shfl_down(c, o);
    l1 += __shfl_down(l1, o);
    l2 += __shfl_down(l2, o);
  }
  const int w = t >> 6;
  if ((t & 63) == 0) { red[0][w] = c; red[1][w] = l1; red[2][w] = l2; }
  __syncthreads();
  if (t == 0) {
    float cs  = red[0][0] + red[0][1] + red[0][2] + red[0][3];
    float l1s = red[1][0] + red[1][1] + red[1][2] + red[1][3];
    float l2s = red[2][0] + red[2][1] + red[2][2] + red[2][3];
    float loss = l1s / cs;                   // reference divides unconditionally
    loss += (cs > 0.0f) ? (l2s / cs) : 0.0f; // guarded second term, as in ref
    out[0] = loss;
  }
}

extern "C" void kernel_launch(void* const* d_in, const int* in_sizes, int n_in,
                              void* d_out, int out_size, void* d_ws, size_t ws_size,
                              hipStream_t stream) {
  (void)in_sizes; (void)n_in; (void)out_size;
  const float* imFtr  = (const float*)d_in[0];
  const float* disFtr = (const float*)d_in[1];
  const int*   lbl    = (const int*)d_in[2];
  float* out = (float*)d_out;

  const size_t disB_bytes = (size_t)NB * ND * sizeof(short);      // 512 KB
  const size_t half_bytes = (size_t)NB * NB * sizeof(float);      // 256 KB
  const size_t need = disB_bytes + 2 * half_bytes + 3 * NB * sizeof(float);

  if (ws_size >= need) {
    short* disB    = (short*)d_ws;
    float* simHalf = (float*)((char*)d_ws + disB_bytes);          // [2][NB][NB]
    float* partial = (float*)((char*)d_ws + disB_bytes + 2 * half_bytes);

    cvtB_kernel<<<dim3(NB), dim3(256), 0, stream>>>(disFtr, disB);
    simmax_half_kernel<<<dim3(NB, 2), dim3(512), 0, stream>>>(imFtr, disB, simHalf);
    loss_kernel<<<dim3(NB), dim3(256), 0, stream>>>(simHalf, simHalf + (size_t)NB * NB,
                                                    lbl, partial);
    finalize_kernel<<<dim3(1), dim3(256), 0, stream>>>(partial, out);
  } else {
    float* simMax  = (float*)d_ws;                                // 256 KB
    float* partial = (float*)((char*)d_ws + (size_t)NB * NB * 4);
    simmax_fallback_kernel<<<dim3(NB), dim3(512), 0, stream>>>(imFtr, disFtr, simMax);
    loss_kernel<<<dim3(NB), dim3(256), 0, stream>>>(simMax, simMax, lbl, partial);
    finalize_kernel<<<dim3(1), dim3(256), 0, stream>>>(partial, out);
  }
}